// Round 9
// baseline (123.348 us; speedup 1.0000x reference)
//
// v9: k_weights loop-nest inverted — all 64 x channels in VGPRs (in-order
// vector loads, counted vmcnt), then per-o one batched 64-float W s_load
// group + one lgkmcnt drain + 64 FMAs. Drains/wave: 160 -> 20, work/drain
// 16 -> 128 cyc. Geometry = v8 (512 blocks, exact 2/CU). k_conv = v4.
#include <hip/hip_runtime.h>

#define T 8
#define C 512
#define HW 196
#define NSEG 16                  // n
#define NT (NSEG * T)            // 128
#define B_TOT (NSEG * HW)        // 3136
#define NH 4
#define KK 5
#define NO 20                    // NH*KK
#define S_SPLIT 8                // channel chunks = waves per block
#define CCH (C / S_SPLIT)        // 64 channels per chunk
#define COLS 49                  // columns per block: 25088/49 = 512 blocks
#define LDSC 64                  // padded col dim for LDS

// ---------------------------------------------------------------------------
// Kernel 1: fused logits + LDS chunk-reduction + softmax -> weights.
// Grid 512 x 512thr; wave w = chunk w (readfirstlane-pinned -> scalar W).
// ---------------------------------------------------------------------------
__global__ __launch_bounds__(512, 4) void k_weights(const float* __restrict__ x,
                                                    const float* __restrict__ W,
                                                    float* __restrict__ wgt) {
    __shared__ float plds[S_SPLIT][NO][LDSC];   // 40960 B

    const int tid  = threadIdx.x;
    const int lane = tid & 63;
    const int sch  = tid >> 6;                  // wave index = channel chunk
    const int cbase = __builtin_amdgcn_readfirstlane(sch * CCH);  // SGPR

    const int nt  = blockIdx.x >> 2;            // block-uniform
    const int hw0 = (blockIdx.x & 3) * COLS;
    const int hw  = hw0 + (lane < COLS ? lane : COLS - 1);  // clamp in-bounds

    const float* xp = x + ((size_t)nt * C + cbase) * HW + hw;
    const float* Wb = W + cbase;                // wave-uniform base -> s_load

    // ---- all 64 channel x values into VGPRs; vector loads are in-order so
    // the compiler pipelines vmcnt(N) waits into the first FMA groups ----
    float xr[CCH];
#pragma unroll
    for (int u = 0; u < CCH; ++u) xr[u] = xp[u * HW];

    // ---- per output o: one 64-float W batch (8 x s_load_dwordx8), one
    // lgkmcnt drain, 64 FMAs. Channel order u ascending == v4's (c0,u)
    // nesting -> bitwise-identical partial logits. ----
    float acc[NO];
#pragma unroll
    for (int o = 0; o < NO; ++o) {
        const float* wr = Wb + o * C;           // wave-uniform
        float a = 0.f;
#pragma unroll
        for (int u = 0; u < CCH; ++u)
            a = fmaf(xr[u], wr[u], a);
        acc[o] = a;
    }

    // partials: lane-consecutive -> 2-way bank aliasing max (free on CDNA4)
#pragma unroll
    for (int o = 0; o < NO; ++o) plds[sch][o][lane] = acc[o];
    __syncthreads();

    // reduce over chunks (s-order 0..7 -> numerics identical), softmax over
    // 5 taps. 196 threads: (head 0..3) x (col 0..48).
    if (tid < COLS * NH) {
        const int h   = tid / COLS;
        const int col = tid - h * COLS;
        const int t   = nt & (T - 1);
        const int n   = nt >> 3;                // nt / T
        const int b   = n * HW + hw0 + col;

        float lg[KK];
#pragma unroll
        for (int k = 0; k < KK; ++k) {
            float sm = 0.f;
#pragma unroll
            for (int s2 = 0; s2 < S_SPLIT; ++s2)
                sm += plds[s2][h * KK + k][col];
            lg[k] = sm;
        }

        float m = lg[0];
#pragma unroll
        for (int k = 1; k < KK; ++k) m = fmaxf(m, lg[k]);
        float e[KK];
        float sum = 0.f;
#pragma unroll
        for (int k = 0; k < KK; ++k) {
            e[k] = __expf(lg[k] - m);
            sum += e[k];
        }
        const float r = 1.f / sum;
#pragma unroll
        for (int k = 0; k < KK; ++k)
            wgt[((size_t)((t * NH + h) * KK + k)) * B_TOT + b] = e[k] * r;
    }
}

// ---------------------------------------------------------------------------
// Kernel 2: causal dynamic conv, one thread per (n, c, hw) — v4 scalar
// version verbatim (float2 variant measured worse; at ~8 µs floor).
// ---------------------------------------------------------------------------
__global__ __launch_bounds__(256) void k_conv(const float* __restrict__ x,
                                              const float* __restrict__ wgt,
                                              float* __restrict__ out) {
    const int idx = blockIdx.x * 256 + threadIdx.x;  // < 16*512*196
    const int hw  = idx % HW;
    const int t1  = idx / HW;          // n*C + c
    const int c   = t1 % C;
    const int n   = t1 / C;
    const int h   = c >> 7;            // head
    const int b   = n * HW + hw;

    float w[T][KK];
#pragma unroll
    for (int t = 0; t < T; ++t)
#pragma unroll
        for (int k = 0; k < KK; ++k)
            w[t][k] = wgt[((size_t)((t * NH + h) * KK + k)) * B_TOT + b];

    const size_t base = ((size_t)(n * T) * C + c) * HW + hw;
    float xv[T];
#pragma unroll
    for (int t = 0; t < T; ++t) xv[t] = x[base + (size_t)t * C * HW];

#pragma unroll
    for (int t = 0; t < T; ++t) {
        float acc = 0.f;
#pragma unroll
        for (int k = 0; k < KK; ++k) {
            const int j = t + k - 4;   // causal, zero-padded left
            if (j >= 0) acc = fmaf(w[t][k], xv[j], acc);
        }
        out[base + (size_t)t * C * HW] = acc;
    }
}

// ---------------------------------------------------------------------------
extern "C" void kernel_launch(void* const* d_in, const int* in_sizes, int n_in,
                              void* d_out, int out_size, void* d_ws, size_t ws_size,
                              hipStream_t stream) {
    const float* x = (const float*)d_in[0];   // (128, 512, 14, 14)
    const float* W = (const float*)d_in[1];   // (20, 512)
    float* out = (float*)d_out;               // (128, 512, 14, 14)

    float* wgt = (float*)d_ws;                // 160 * 3136 floats = 2 MB

    k_weights<<<dim3(NT * 4), 512, 0, stream>>>(x, W, wgt);   // 512 blocks
    k_conv<<<dim3((NSEG * C * HW) / 256), 256, 0, stream>>>(x, wgt, out);
}

// Round 10
// 121.815 us; speedup vs baseline: 1.0126x; 1.0126x over previous
//
// v10: unconfounded retest of deep x-ILP — xr[64] loaded upfront (64 loads
// in flight, counted vmcnt) + v4's exact c0/o/u FMA nesting (20 independent
// acc chains, batched scalar-W per c0). Numerics bit-identical to v4/v8.
// Geometry = v8 (512 blocks, exact 2/CU). k_conv = v4 scalar.
#include <hip/hip_runtime.h>

#define T 8
#define C 512
#define HW 196
#define NSEG 16                  // n
#define NT (NSEG * T)            // 128
#define B_TOT (NSEG * HW)        // 3136
#define NH 4
#define KK 5
#define NO 20                    // NH*KK
#define S_SPLIT 8                // channel chunks = waves per block
#define CCH (C / S_SPLIT)        // 64 channels per chunk
#define COLS 49                  // columns per block: 25088/49 = 512 blocks
#define LDSC 64                  // padded col dim for LDS

// ---------------------------------------------------------------------------
// Kernel 1: fused logits + LDS chunk-reduction + softmax -> weights.
// Grid 512 x 512thr; wave w = chunk w (readfirstlane-pinned -> scalar W).
// ---------------------------------------------------------------------------
__global__ __launch_bounds__(512, 4) void k_weights(const float* __restrict__ x,
                                                    const float* __restrict__ W,
                                                    float* __restrict__ wgt) {
    __shared__ float plds[S_SPLIT][NO][LDSC];   // 40960 B

    const int tid  = threadIdx.x;
    const int lane = tid & 63;
    const int sch  = tid >> 6;                  // wave index = channel chunk
    const int cbase = __builtin_amdgcn_readfirstlane(sch * CCH);  // SGPR

    const int nt  = blockIdx.x >> 2;            // block-uniform
    const int hw0 = (blockIdx.x & 3) * COLS;
    const int hw  = hw0 + (lane < COLS ? lane : COLS - 1);  // clamp in-bounds

    const float* xp = x + ((size_t)nt * C + cbase) * HW + hw;
    const float* Wb = W + cbase;                // wave-uniform base -> s_load

    // ---- all 64 channel x values issued upfront: 64 loads in flight,
    // in-order vector returns -> compiler drains with counted vmcnt into
    // the first FMA blocks (8x the in-flight depth of v4's dist-1) ----
    float xr[CCH];
#pragma unroll
    for (int u = 0; u < CCH; ++u) xr[u] = xp[u * HW];

    // ---- v4's exact FMA nesting: c0-blocks of 8, o-mid, u-inner.
    // 20 independent acc chains; per-c0 batched wave-uniform W s_loads.
    // Per-acc channel order = ascending 0..63 -> bitwise-identical to v4. ----
    float acc[NO];
#pragma unroll
    for (int o = 0; o < NO; ++o) acc[o] = 0.f;

#pragma unroll
    for (int c0 = 0; c0 < CCH; c0 += 8) {
        const float* wr = Wb + c0;              // wave-uniform
#pragma unroll
        for (int o = 0; o < NO; ++o) {
#pragma unroll
            for (int u = 0; u < 8; ++u)
                acc[o] = fmaf(xr[c0 + u], wr[o * C + u], acc[o]);
        }
    }

    // partials: lane-consecutive -> 2-way bank aliasing max (free on CDNA4)
#pragma unroll
    for (int o = 0; o < NO; ++o) plds[sch][o][lane] = acc[o];
    __syncthreads();

    // reduce over chunks (s-order 0..7 -> numerics identical), softmax over
    // 5 taps. 196 threads: (head 0..3) x (col 0..48).
    if (tid < COLS * NH) {
        const int h   = tid / COLS;
        const int col = tid - h * COLS;
        const int t   = nt & (T - 1);
        const int n   = nt >> 3;                // nt / T
        const int b   = n * HW + hw0 + col;

        float lg[KK];
#pragma unroll
        for (int k = 0; k < KK; ++k) {
            float sm = 0.f;
#pragma unroll
            for (int s2 = 0; s2 < S_SPLIT; ++s2)
                sm += plds[s2][h * KK + k][col];
            lg[k] = sm;
        }

        float m = lg[0];
#pragma unroll
        for (int k = 1; k < KK; ++k) m = fmaxf(m, lg[k]);
        float e[KK];
        float sum = 0.f;
#pragma unroll
        for (int k = 0; k < KK; ++k) {
            e[k] = __expf(lg[k] - m);
            sum += e[k];
        }
        const float r = 1.f / sum;
#pragma unroll
        for (int k = 0; k < KK; ++k)
            wgt[((size_t)((t * NH + h) * KK + k)) * B_TOT + b] = e[k] * r;
    }
}

// ---------------------------------------------------------------------------
// Kernel 2: causal dynamic conv, one thread per (n, c, hw) — v4 scalar
// version verbatim (float2 variant measured worse; at ~8 µs floor).
// ---------------------------------------------------------------------------
__global__ __launch_bounds__(256) void k_conv(const float* __restrict__ x,
                                              const float* __restrict__ wgt,
                                              float* __restrict__ out) {
    const int idx = blockIdx.x * 256 + threadIdx.x;  // < 16*512*196
    const int hw  = idx % HW;
    const int t1  = idx / HW;          // n*C + c
    const int c   = t1 % C;
    const int n   = t1 / C;
    const int h   = c >> 7;            // head
    const int b   = n * HW + hw;

    float w[T][KK];
#pragma unroll
    for (int t = 0; t < T; ++t)
#pragma unroll
        for (int k = 0; k < KK; ++k)
            w[t][k] = wgt[((size_t)((t * NH + h) * KK + k)) * B_TOT + b];

    const size_t base = ((size_t)(n * T) * C + c) * HW + hw;
    float xv[T];
#pragma unroll
    for (int t = 0; t < T; ++t) xv[t] = x[base + (size_t)t * C * HW];

#pragma unroll
    for (int t = 0; t < T; ++t) {
        float acc = 0.f;
#pragma unroll
        for (int k = 0; k < KK; ++k) {
            const int j = t + k - 4;   // causal, zero-padded left
            if (j >= 0) acc = fmaf(w[t][k], xv[j], acc);
        }
        out[base + (size_t)t * C * HW] = acc;
    }
}

// ---------------------------------------------------------------------------
extern "C" void kernel_launch(void* const* d_in, const int* in_sizes, int n_in,
                              void* d_out, int out_size, void* d_ws, size_t ws_size,
                              hipStream_t stream) {
    const float* x = (const float*)d_in[0];   // (128, 512, 14, 14)
    const float* W = (const float*)d_in[1];   // (20, 512)
    float* out = (float*)d_out;               // (128, 512, 14, 14)

    float* wgt = (float*)d_ws;                // 160 * 3136 floats = 2 MB

    k_weights<<<dim3(NT * 4), 512, 0, stream>>>(x, W, wgt);   // 512 blocks
    k_conv<<<dim3((NSEG * C * HW) / 256), 256, 0, stream>>>(x, wgt, out);
}